// Round 15
// baseline (242.556 us; speedup 1.0000x reference)
//
#include <hip/hip_runtime.h>
#include <hip/hip_fp16.h>

// Softmax attention (mask is a no-op). B=4, S=4096, D=256, fp32 in/out.
// Round 15 (from r14's 166.9us):
//  (1) Q/K proj 3-term -> 1-term: Qf/Kf are STORED fp16, so hi/lo accuracy
//      was re-rounded at store anyway (delta-score 0.007->0.012; predicted
//      absmax ~0.05-0.07 vs 0.1019 threshold). Kills Wtl + 2/3 of proj MFMA.
//  (2) proj epilogues via LDS transpose: Q/K/V global writes become
//      contiguous f16x8 (was 2B/8B scatter with RMW amplification).
//  (3) combine fused into attn: last-finisher per (b,qi) group via
//      __threadfence + device-scope atomicAdd on 64B-padded counters (G16).
//      3 dispatches total. attn8 main loop VERBATIM (111us validated).

typedef _Float16 f16x8 __attribute__((ext_vector_type(8)));
typedef _Float16 f16x4 __attribute__((ext_vector_type(4)));
typedef __fp16   fp16x2 __attribute__((ext_vector_type(2)));
typedef float    f32x4 __attribute__((ext_vector_type(4)));
typedef float    f32x16 __attribute__((ext_vector_type(16)));

#define MFMA16(A, B, C) __builtin_amdgcn_mfma_f32_16x16x32_f16((A), (B), (C), 0, 0, 0)
#define MFMA32(A, B, C) __builtin_amdgcn_mfma_f32_32x32x16_f16((A), (B), (C), 0, 0, 0)

static __device__ __forceinline__ void gload16(const _Float16* g, _Float16* l) {
    __builtin_amdgcn_global_load_lds(
        (unsigned int __attribute__((address_space(1)))*)g,
        (unsigned int __attribute__((address_space(3)))*)l, 16, 0, 0);
}

static __device__ __forceinline__ unsigned packh(float a, float b) {
    union { fp16x2 h; unsigned u; } x;
    x.h = __builtin_amdgcn_cvt_pkrtz(a, b);
    return x.u;
}

static __device__ __forceinline__ float fexp2(float x) {
    float r;
    asm("v_exp_f32 %0, %1" : "=v"(r) : "v"(x));
    return r;
}

static __device__ __forceinline__ void load_xfrag_hi(const float* xp, f16x8& Ah) {
    float4 a0 = *(const float4*)xp;
    float4 a1 = *(const float4*)(xp + 4);
    float v[8] = {a0.x, a0.y, a0.z, a0.w, a1.x, a1.y, a1.z, a1.w};
#pragma unroll
    for (int j = 0; j < 8; ++j) Ah[j] = (_Float16)v[j];
}

// ---- kernel 1: W -> W^T fp16 FRAGMENT-LINEAR (f16x8 stores) + cnt zero ----
__global__ __launch_bounds__(256) void convert_w_kernel(
    const float* __restrict__ Wq, const float* __restrict__ Wk, const float* __restrict__ Wv,
    _Float16* __restrict__ Wth, int* __restrict__ cnt, int* __restrict__ done)
{
    if (blockIdx.x == 0) {
        if (threadIdx.x < 8)   cnt[threadIdx.x * 64] = 0;
        if (threadIdx.x < 128) done[threadIdx.x * 16] = 0;
    }
    int idx = blockIdx.x * 256 + threadIdx.x;   // [0, 24576)
    int mat = idx >> 13, f_l = idx & 8191;      // f_l = frag*64 + lane
    int frag = f_l >> 6, lane = f_l & 63;
    int ks = frag >> 4, nt = frag & 15;
    int n = nt * 16 + (lane & 15);
    int k0 = ks * 32 + ((lane >> 4) & 3) * 8;
    const float* W = (mat == 0) ? Wq : (mat == 1) ? Wk : Wv;
    f16x8 h;
#pragma unroll
    for (int j = 0; j < 8; ++j) h[j] = (_Float16)W[(k0 + j) * 256 + n];
    *(f16x8*)(Wth + mat * 65536 + (size_t)f_l * 8) = h;
}

// ------------- kernel 2: ALL projections, 1-term, LDS-transposed writes -----
// MODE 0 = Q (*log2e), 1 = K, 2 = V (V^T layout)
template <int MODE>
static __device__ __forceinline__ void proj_body(
    const float* __restrict__ x, const _Float16* __restrict__ Wh,
    const float* __restrict__ bias, _Float16* __restrict__ dst,
    _Float16* __restrict__ lds)
{
    const int tid = threadIdx.x, wid = tid >> 6, lane = tid & 63;
    const int lrow = lane & 15, lgrp = lane >> 4;
    const int rb = blockIdx.x * 4 + wid;
    const int row0 = rb * 16;

    f32x4 acc[16];
#pragma unroll
    for (int i = 0; i < 16; ++i) acc[i] = f32x4{0.f, 0.f, 0.f, 0.f};

#pragma unroll
    for (int ks = 0; ks < 8; ++ks) {
        f16x8 Ah;
        load_xfrag_hi(x + (size_t)(row0 + lrow) * 256 + ks * 32 + lgrp * 8, Ah);
#pragma unroll
        for (int nt = 0; nt < 16; ++nt) {
            f16x8 Bh = *(const f16x8*)(Wh + ((ks * 16 + nt) * 64 + lane) * 8);
            acc[nt] = MFMA16(Ah, Bh, acc[nt]);
        }
    }

    const float LOG2E = 1.4426950408889634f;
    if constexpr (MODE == 2) {
        // LDS as [n][72] (pad->16B align), chunk XOR c^(n&7) vs readout
        const int m_l = wid * 16 + lgrp * 4;
        const int cm = m_l >> 3, oic = (lgrp & 1) * 4;
#pragma unroll
        for (int nt = 0; nt < 16; ++nt) {
            const int n = nt * 16 + lrow;
            const float bb = bias[n];
            f16x4 v;
#pragma unroll
            for (int r = 0; r < 4; ++r) v[r] = (_Float16)(acc[nt][r] + bb);
            *(f16x4*)(lds + n * 72 + (cm ^ (n & 7)) * 8 + oic) = v;
        }
        __syncthreads();
#pragma unroll
        for (int it = 0; it < 8; ++it) {
            const int u = it * 256 + tid;       // 2048 units
            const int n = u >> 3, c = u & 7;
            f16x8 v = *(const f16x8*)(lds + n * 72 + ((c ^ (n & 7))) * 8);
            *(f16x8*)(dst + (size_t)n * 16384 + blockIdx.x * 64 + c * 8) = v;
        }
    } else {
        // LDS as [row_l][264] (pad->16B align rows)
        const float s = (MODE == 0) ? LOG2E : 1.0f;
#pragma unroll
        for (int nt = 0; nt < 16; ++nt) {
            const int n = nt * 16 + lrow;
            const float bb = bias[n];
#pragma unroll
            for (int r = 0; r < 4; ++r) {
                const int row_l = wid * 16 + lgrp * 4 + r;
                lds[row_l * 264 + n] = (_Float16)((acc[nt][r] + bb) * s);
            }
        }
        __syncthreads();
#pragma unroll
        for (int it = 0; it < 8; ++it) {
            const int u = it * 256 + tid;       // 2048 units
            const int row_l = u >> 5, c = u & 31;
            f16x8 v = *(const f16x8*)(lds + row_l * 264 + c * 8);
            *(f16x8*)(dst + ((size_t)blockIdx.x * 64 + row_l) * 256 + c * 8) = v;
        }
    }
}

__global__ __launch_bounds__(256) void proj_all_kernel(
    const float* __restrict__ x, const _Float16* __restrict__ Wth,
    const float* __restrict__ bq, const float* __restrict__ bk,
    const float* __restrict__ bv,
    _Float16* __restrict__ Qf, _Float16* __restrict__ Kf, _Float16* __restrict__ Vt)
{
    __shared__ _Float16 lds[18432];   // max(64*264, 256*72) = 18432 f16
    const int m = blockIdx.y;
    if (m == 0)      proj_body<0>(x, Wth,          bq, Qf, lds);
    else if (m == 1) proj_body<1>(x, Wth + 65536,  bk, Kf, lds);
    else             proj_body<2>(x, Wth + 131072, bv, Vt, lds);
}

// -------- kernel 3: attn8 (r10/r14 loop VERBATIM) + fused combine -----------
__global__ __launch_bounds__(256, 2) void attn8_kernel(
    const _Float16* __restrict__ Qf, const _Float16* __restrict__ Kf,
    const _Float16* __restrict__ Vt, _Float16* __restrict__ Op01,
    _Float16* __restrict__ Op23, float* __restrict__ ml, int* __restrict__ cnt,
    int* __restrict__ done, float* __restrict__ out)
{
    __shared__ _Float16 Kb[2][32 * 256];   // [key][d] 512B rows, 16KB/buf
    __shared__ _Float16 Vb[2][256 * 32];   // [d][key] 64B rows,  16KB/buf
    __shared__ int s_item;

    const int tid = threadIdx.x, wid = tid >> 6, lane = tid & 63;
    const int lq = lane & 31, hi = lane >> 5;

    if (tid == 0) {
        int xcd;
        asm volatile("s_getreg_b32 %0, hwreg(HW_REG_XCC_ID)" : "=s"(xcd));
        xcd &= 7;
        int item = -1;
#pragma unroll 1
        for (int k = 0; k < 8; ++k) {
            const int qidx = (xcd + k) & 7;
            int v = atomicAdd(cnt + qidx * 64, 1);   // padded: 256B apart
            if (v < 64) { item = qidx * 64 + v; break; }
        }
        s_item = item;                               // exactly-once handout
    }
    __syncthreads();
    const int item = s_item;
    const int group = (item >> 6) * 2 + ((item & 63) >> 5);  // [0,16)
    const int qi = item & 31;
    const int b = group >> 2, split = group & 3;
    const size_t bS = (size_t)b * 4096;
    const size_t qrow = bS + qi * 128 + wid * 32;
    const size_t k0g = bS + (size_t)split * 1024;
    const int NT = 32;                                       // 1024 / 32

    f16x8 QB[16];
#pragma unroll
    for (int ks = 0; ks < 16; ++ks)
        QB[ks] = *(const f16x8*)(Qf + (qrow + lq) * 256 + ks * 16 + hi * 8);

    f32x16 Oacc[8];
#pragma unroll
    for (int i = 0; i < 8; ++i)
#pragma unroll
        for (int r = 0; r < 16; ++r) Oacc[i][r] = 0.f;
    float m_r = -1e30f, l_r = 0.f;

    auto stage = [&](int buf, int t) {
        const size_t krow = k0g + (size_t)t * 32;
#pragma unroll
        for (int it = 0; it < 4; ++it) {   // K: 1024 slots, 5-bit XOR swz src
            const int s = it * 256 + tid;
            const int row = s >> 5, c = s & 31;
            const int src = c ^ (row & 7) ^ (((row >> 3) & 3) << 3);
            gload16(Kf + (krow + row) * 256 + src * 8, &Kb[buf][s * 8]);
        }
#pragma unroll
        for (int it = 0; it < 4; ++it) {   // V^T: 1024 slots, 2-bit XOR swz
            const int s = it * 256 + tid;
            const int d = s >> 2, c = s & 3;
            gload16(Vt + (size_t)d * 16384 + krow + ((c ^ ((d >> 1) & 3)) * 8), &Vb[buf][s * 8]);
        }
    };

    stage(0, 0);
    asm volatile("s_waitcnt vmcnt(0)" ::: "memory");
    __builtin_amdgcn_s_barrier();

    const float THR = 10.0f;
    const int kx = (lq & 7) ^ (((lq >> 3) & 3) << 3);
    const int vx = (lq >> 1) & 3;
    int buf = 0;
    for (int t = 0; t < NT; ++t) {
        if (t + 1 < NT) stage(buf ^ 1, t + 1);
        const _Float16* K_ = Kb[buf];
        const _Float16* V_ = Vb[buf];

        // ---- QK: S^T[key=lq][q col], 16 MFMAs ----
        f32x16 sc;
#pragma unroll
        for (int r = 0; r < 16; ++r) sc[r] = 0.f;
#pragma unroll
        for (int ks = 0; ks < 16; ++ks) {
            const int slot = (2 * ks + hi) ^ kx;
            f16x8 Ak = *(const f16x8*)((const char*)K_ + lq * 512 + slot * 16);
            sc = MFMA32(Ak, QB[ks], sc);
        }

        // ---- per-lane online softmax (lane owns q = lq) ----
        float tm[8];
#pragma unroll
        for (int j = 0; j < 8; ++j) tm[j] = fmaxf(sc[j], sc[j + 8]);
#pragma unroll
        for (int s = 4; s > 0; s >>= 1)
#pragma unroll
            for (int j = 0; j < s; ++j) tm[j] = fmaxf(tm[j], tm[j + s]);
        float mx = fmaxf(tm[0], __shfl_xor(tm[0], 32));
        if (__any(mx > m_r + THR)) {
            const float mn = fmaxf(m_r, mx);
            const float scl = fexp2(m_r - mn);
            m_r = mn; l_r *= scl;
#pragma unroll
            for (int i = 0; i < 8; ++i)
#pragma unroll
                for (int r = 0; r < 16; ++r) Oacc[i][r] *= scl;
        }

        float p[16];
#pragma unroll
        for (int r = 0; r < 16; ++r) p[r] = fexp2(sc[r] - m_r);
        float ts[8];
#pragma unroll
        for (int j = 0; j < 8; ++j) ts[j] = p[j] + p[j + 8];
#pragma unroll
        for (int s = 4; s > 0; s >>= 1)
#pragma unroll
            for (int j = 0; j < s; ++j) ts[j] += ts[j + s];
        l_r += ts[0] + __shfl_xor(ts[0], 32);

        unsigned w[8], pw[8];
#pragma unroll
        for (int j = 0; j < 8; ++j) {
            w[j] = packh(p[2 * j], p[2 * j + 1]);
            pw[j] = __shfl_xor(w[j], 32);
        }
        f16x8 Pfrag[2];
#pragma unroll
        for (int s = 0; s < 2; ++s) {
            unsigned f0 = hi ? pw[4 * s + 2] : w[4 * s + 0];
            unsigned f1 = hi ? pw[4 * s + 3] : w[4 * s + 1];
            unsigned f2 = hi ? w[4 * s + 2] : pw[4 * s + 0];
            unsigned f3 = hi ? w[4 * s + 3] : pw[4 * s + 1];
            union { unsigned u[4]; f16x8 f; } cvt;
            cvt.u[0] = f0; cvt.u[1] = f1; cvt.u[2] = f2; cvt.u[3] = f3;
            Pfrag[s] = cvt.f;
        }

        // ---- PV: O^T[d][q] += V^T.P, 16 MFMAs (8 independent chains) ----
#pragma unroll
        for (int dblk = 0; dblk < 8; ++dblk) {
#pragma unroll
            for (int kstep = 0; kstep < 2; ++kstep) {
                const int slot = (kstep * 2 + hi) ^ vx;
                f16x8 Av = *(const f16x8*)((const char*)V_ + (dblk * 32 + lq) * 64 + slot * 16);
                Oacc[dblk] = MFMA32(Av, Pfrag[kstep], Oacc[dblk]);
            }
        }

        asm volatile("s_waitcnt vmcnt(0)" ::: "memory");
        __builtin_amdgcn_s_barrier();
        buf ^= 1;
    }

    // ---- epilogue: normalized fp16 partial + (m, l) ----
    _Float16* Ops = (split < 2) ? (Op01 + (size_t)split * 4194304)
                                : (Op23 + (size_t)(split - 2) * 4194304);
    const float inv = 1.0f / l_r;
    const size_t grow = qrow + lq;
#pragma unroll
    for (int dblk = 0; dblk < 8; ++dblk)
#pragma unroll
        for (int quad = 0; quad < 4; ++quad) {
            f16x4 o;
#pragma unroll
            for (int j = 0; j < 4; ++j) o[j] = (_Float16)(Oacc[dblk][quad * 4 + j] * inv);
            *(f16x4*)(Ops + grow * 256 + dblk * 32 + 8 * quad + 4 * hi) = o;
        }
    if (hi == 0) {
        ml[((size_t)split * 16384 + grow) * 2]     = m_r;
        ml[((size_t)split * 16384 + grow) * 2 + 1] = l_r;
    }

    // ---- fused split-K combine: last finisher of (b,qi) group reduces ----
    __threadfence();                         // release partials (device scope)
    __shared__ int s_last;
    if (tid == 0) {
        const int gid = b * 32 + qi;
        s_last = (atomicAdd(done + gid * 16, 1) == 3);
    }
    __syncthreads();
    if (s_last) {
        __threadfence();                     // acquire other splits' partials
        const size_t row0g = bS + (size_t)qi * 128;
        const int rbase = tid >> 5;          // 0..7
        const int c0 = (tid & 31) * 8;       // 0..248
#pragma unroll 1
        for (int rr = 0; rr < 16; ++rr) {
            const size_t row = row0g + rbase * 16 + rr;
            float m_s[4], l_s[4], wgt[4];
            float M = -1e30f;
#pragma unroll
            for (int s = 0; s < 4; ++s) {
                m_s[s] = ml[((size_t)s * 16384 + row) * 2];
                l_s[s] = ml[((size_t)s * 16384 + row) * 2 + 1];
                M = fmaxf(M, m_s[s]);
            }
            float Wsum = 0.f;
#pragma unroll
            for (int s = 0; s < 4; ++s) { wgt[s] = l_s[s] * fexp2(m_s[s] - M); Wsum += wgt[s]; }
            const float winv = 1.0f / Wsum;
            float acc2[8] = {0.f, 0.f, 0.f, 0.f, 0.f, 0.f, 0.f, 0.f};
#pragma unroll
            for (int s = 0; s < 4; ++s) {
                const _Float16* Op = (s < 2) ? (Op01 + (size_t)s * 4194304)
                                             : (Op23 + (size_t)(s - 2) * 4194304);
                f16x8 v = *(const f16x8*)(Op + row * 256 + c0);
#pragma unroll
                for (int j = 0; j < 8; ++j) acc2[j] += wgt[s] * (float)v[j];
            }
            float4 o0 = {acc2[0] * winv, acc2[1] * winv, acc2[2] * winv, acc2[3] * winv};
            float4 o1 = {acc2[4] * winv, acc2[5] * winv, acc2[6] * winv, acc2[7] * winv};
            *(float4*)(out + row * 256 + c0) = o0;
            *(float4*)(out + row * 256 + c0 + 4) = o1;
        }
    }
}

extern "C" void kernel_launch(void* const* d_in, const int* in_sizes, int n_in,
                              void* d_out, int out_size, void* d_ws, size_t ws_size,
                              hipStream_t stream) {
    const float* x  = (const float*)d_in[0];
    const float* Wq = (const float*)d_in[1];
    const float* bq = (const float*)d_in[2];
    const float* Wk = (const float*)d_in[3];
    const float* bk = (const float*)d_in[4];
    const float* Wv = (const float*)d_in[5];
    const float* bv = (const float*)d_in[6];
    float* out = (float*)d_out;

    // ws: Op01 (16MB) | Qf | Kf | Vt | Wth | ml | Op23 (16MB) | cnt | done
    _Float16* Op01 = (_Float16*)d_ws;
    _Float16* Qf  = Op01 + 2 * 4194304;
    _Float16* Kf  = Qf  + 4194304;
    _Float16* Vt  = Kf  + 4194304;
    _Float16* Wth = Vt  + 4194304;
    float*    ml  = (float*)(Wth + 196608);            // 4*16384*2 f32 = 512KB
    _Float16* Op23 = (_Float16*)((char*)ml + 524288);  // splits 2,3 (16MB)
    int*      cnt  = (int*)(Op23 + 2 * 4194304);       // 8 ints, 256B apart
    int*      done = cnt + 512;                        // 128 ints, 64B apart

    convert_w_kernel<<<96, 256, 0, stream>>>(Wq, Wk, Wv, Wth, cnt, done);
    proj_all_kernel<<<dim3(256, 3), 256, 0, stream>>>(x, Wth, bq, bk, bv, Qf, Kf, Vt);
    attn8_kernel<<<512, 256, 0, stream>>>(Qf, Kf, Vt, Op01, Op23, ml, cnt, done, out);
}

// Round 16
// 143.297 us; speedup vs baseline: 1.6927x; 1.6927x over previous
//
#include <hip/hip_runtime.h>
#include <hip/hip_fp16.h>

// Softmax attention (mask is a no-op). B=4, S=4096, D=256, fp32 in/out.
// Round 16: r15 post-mortem — fused combine's __threadfence() (device scope)
// forces per-XCD L2 writeback/invalidate, nuking co-resident blocks' K/V
// locality (attn 111->230us, FETCH 21->36MB). LAW: no device-scope fences
// inside L2-locality-critical kernels on multi-XCD CDNA4.
// Keep r15's validated wins: 1-term Q/K proj (absmax 0.047 <= 0.1019),
// LDS-transposed proj epilogues, f16x8 convert_w.
// attn8 reverted to r14 form VERBATIM (111us); combine separate (512 blk).

typedef _Float16 f16x8 __attribute__((ext_vector_type(8)));
typedef _Float16 f16x4 __attribute__((ext_vector_type(4)));
typedef __fp16   fp16x2 __attribute__((ext_vector_type(2)));
typedef float    f32x4 __attribute__((ext_vector_type(4)));
typedef float    f32x16 __attribute__((ext_vector_type(16)));

#define MFMA16(A, B, C) __builtin_amdgcn_mfma_f32_16x16x32_f16((A), (B), (C), 0, 0, 0)
#define MFMA32(A, B, C) __builtin_amdgcn_mfma_f32_32x32x16_f16((A), (B), (C), 0, 0, 0)

static __device__ __forceinline__ void gload16(const _Float16* g, _Float16* l) {
    __builtin_amdgcn_global_load_lds(
        (unsigned int __attribute__((address_space(1)))*)g,
        (unsigned int __attribute__((address_space(3)))*)l, 16, 0, 0);
}

static __device__ __forceinline__ unsigned packh(float a, float b) {
    union { fp16x2 h; unsigned u; } x;
    x.h = __builtin_amdgcn_cvt_pkrtz(a, b);
    return x.u;
}

static __device__ __forceinline__ float fexp2(float x) {
    float r;
    asm("v_exp_f32 %0, %1" : "=v"(r) : "v"(x));
    return r;
}

static __device__ __forceinline__ void load_xfrag_hi(const float* xp, f16x8& Ah) {
    float4 a0 = *(const float4*)xp;
    float4 a1 = *(const float4*)(xp + 4);
    float v[8] = {a0.x, a0.y, a0.z, a0.w, a1.x, a1.y, a1.z, a1.w};
#pragma unroll
    for (int j = 0; j < 8; ++j) Ah[j] = (_Float16)v[j];
}

// ---- kernel 1: W -> W^T fp16 FRAGMENT-LINEAR (f16x8 stores) + cnt zero ----
__global__ __launch_bounds__(256) void convert_w_kernel(
    const float* __restrict__ Wq, const float* __restrict__ Wk, const float* __restrict__ Wv,
    _Float16* __restrict__ Wth, int* __restrict__ cnt)
{
    if (blockIdx.x == 0 && threadIdx.x < 8) cnt[threadIdx.x * 64] = 0;
    int idx = blockIdx.x * 256 + threadIdx.x;   // [0, 24576)
    int mat = idx >> 13, f_l = idx & 8191;      // f_l = frag*64 + lane
    int frag = f_l >> 6, lane = f_l & 63;
    int ks = frag >> 4, nt = frag & 15;
    int n = nt * 16 + (lane & 15);
    int k0 = ks * 32 + ((lane >> 4) & 3) * 8;
    const float* W = (mat == 0) ? Wq : (mat == 1) ? Wk : Wv;
    f16x8 h;
#pragma unroll
    for (int j = 0; j < 8; ++j) h[j] = (_Float16)W[(k0 + j) * 256 + n];
    *(f16x8*)(Wth + mat * 65536 + (size_t)f_l * 8) = h;
}

// ------------- kernel 2: ALL projections, 1-term, LDS-transposed writes -----
// MODE 0 = Q (*log2e), 1 = K, 2 = V (V^T layout). (r15-validated)
template <int MODE>
static __device__ __forceinline__ void proj_body(
    const float* __restrict__ x, const _Float16* __restrict__ Wh,
    const float* __restrict__ bias, _Float16* __restrict__ dst,
    _Float16* __restrict__ lds)
{
    const int tid = threadIdx.x, wid = tid >> 6, lane = tid & 63;
    const int lrow = lane & 15, lgrp = lane >> 4;
    const int rb = blockIdx.x * 4 + wid;
    const int row0 = rb * 16;

    f32x4 acc[16];
#pragma unroll
    for (int i = 0; i < 16; ++i) acc[i] = f32x4{0.f, 0.f, 0.f, 0.f};

#pragma unroll
    for (int ks = 0; ks < 8; ++ks) {
        f16x8 Ah;
        load_xfrag_hi(x + (size_t)(row0 + lrow) * 256 + ks * 32 + lgrp * 8, Ah);
#pragma unroll
        for (int nt = 0; nt < 16; ++nt) {
            f16x8 Bh = *(const f16x8*)(Wh + ((ks * 16 + nt) * 64 + lane) * 8);
            acc[nt] = MFMA16(Ah, Bh, acc[nt]);
        }
    }

    const float LOG2E = 1.4426950408889634f;
    if constexpr (MODE == 2) {
        const int m_l = wid * 16 + lgrp * 4;
        const int cm = m_l >> 3, oic = (lgrp & 1) * 4;
#pragma unroll
        for (int nt = 0; nt < 16; ++nt) {
            const int n = nt * 16 + lrow;
            const float bb = bias[n];
            f16x4 v;
#pragma unroll
            for (int r = 0; r < 4; ++r) v[r] = (_Float16)(acc[nt][r] + bb);
            *(f16x4*)(lds + n * 72 + (cm ^ (n & 7)) * 8 + oic) = v;
        }
        __syncthreads();
#pragma unroll
        for (int it = 0; it < 8; ++it) {
            const int u = it * 256 + tid;       // 2048 units
            const int n = u >> 3, c = u & 7;
            f16x8 v = *(const f16x8*)(lds + n * 72 + ((c ^ (n & 7))) * 8);
            *(f16x8*)(dst + (size_t)n * 16384 + blockIdx.x * 64 + c * 8) = v;
        }
    } else {
        const float s = (MODE == 0) ? LOG2E : 1.0f;
#pragma unroll
        for (int nt = 0; nt < 16; ++nt) {
            const int n = nt * 16 + lrow;
            const float bb = bias[n];
#pragma unroll
            for (int r = 0; r < 4; ++r) {
                const int row_l = wid * 16 + lgrp * 4 + r;
                lds[row_l * 264 + n] = (_Float16)((acc[nt][r] + bb) * s);
            }
        }
        __syncthreads();
#pragma unroll
        for (int it = 0; it < 8; ++it) {
            const int u = it * 256 + tid;       // 2048 units
            const int row_l = u >> 5, c = u & 31;
            f16x8 v = *(const f16x8*)(lds + row_l * 264 + c * 8);
            *(f16x8*)(dst + ((size_t)blockIdx.x * 64 + row_l) * 256 + c * 8) = v;
        }
    }
}

__global__ __launch_bounds__(256) void proj_all_kernel(
    const float* __restrict__ x, const _Float16* __restrict__ Wth,
    const float* __restrict__ bq, const float* __restrict__ bk,
    const float* __restrict__ bv,
    _Float16* __restrict__ Qf, _Float16* __restrict__ Kf, _Float16* __restrict__ Vt)
{
    __shared__ _Float16 lds[18432];   // max(64*264, 256*72) = 18432 f16
    const int m = blockIdx.y;
    if (m == 0)      proj_body<0>(x, Wth,          bq, Qf, lds);
    else if (m == 1) proj_body<1>(x, Wth + 65536,  bk, Kf, lds);
    else             proj_body<2>(x, Wth + 131072, bv, Vt, lds);
}

// -------- kernel 3: attn8 — r14 form VERBATIM (111us validated) -------------
__global__ __launch_bounds__(256, 2) void attn8_kernel(
    const _Float16* __restrict__ Qf, const _Float16* __restrict__ Kf,
    const _Float16* __restrict__ Vt, _Float16* __restrict__ Op01,
    _Float16* __restrict__ Op23, float* __restrict__ ml, int* __restrict__ cnt)
{
    __shared__ _Float16 Kb[2][32 * 256];   // [key][d] 512B rows, 16KB/buf
    __shared__ _Float16 Vb[2][256 * 32];   // [d][key] 64B rows,  16KB/buf
    __shared__ int s_item;

    const int tid = threadIdx.x, wid = tid >> 6, lane = tid & 63;
    const int lq = lane & 31, hi = lane >> 5;

    if (tid == 0) {
        int xcd;
        asm volatile("s_getreg_b32 %0, hwreg(HW_REG_XCC_ID)" : "=s"(xcd));
        xcd &= 7;
        int item = -1;
#pragma unroll 1
        for (int k = 0; k < 8; ++k) {
            const int qidx = (xcd + k) & 7;
            int v = atomicAdd(cnt + qidx * 64, 1);   // padded: 256B apart
            if (v < 64) { item = qidx * 64 + v; break; }
        }
        s_item = item;                               // exactly-once handout
    }
    __syncthreads();
    const int item = s_item;
    const int group = (item >> 6) * 2 + ((item & 63) >> 5);  // [0,16)
    const int qi = item & 31;
    const int b = group >> 2, split = group & 3;
    const size_t bS = (size_t)b * 4096;
    const size_t qrow = bS + qi * 128 + wid * 32;
    const size_t k0g = bS + (size_t)split * 1024;
    const int NT = 32;                                       // 1024 / 32

    f16x8 QB[16];
#pragma unroll
    for (int ks = 0; ks < 16; ++ks)
        QB[ks] = *(const f16x8*)(Qf + (qrow + lq) * 256 + ks * 16 + hi * 8);

    f32x16 Oacc[8];
#pragma unroll
    for (int i = 0; i < 8; ++i)
#pragma unroll
        for (int r = 0; r < 16; ++r) Oacc[i][r] = 0.f;
    float m_r = -1e30f, l_r = 0.f;

    auto stage = [&](int buf, int t) {
        const size_t krow = k0g + (size_t)t * 32;
#pragma unroll
        for (int it = 0; it < 4; ++it) {   // K: 1024 slots, 5-bit XOR swz src
            const int s = it * 256 + tid;
            const int row = s >> 5, c = s & 31;
            const int src = c ^ (row & 7) ^ (((row >> 3) & 3) << 3);
            gload16(Kf + (krow + row) * 256 + src * 8, &Kb[buf][s * 8]);
        }
#pragma unroll
        for (int it = 0; it < 4; ++it) {   // V^T: 1024 slots, 2-bit XOR swz
            const int s = it * 256 + tid;
            const int d = s >> 2, c = s & 3;
            gload16(Vt + (size_t)d * 16384 + krow + ((c ^ ((d >> 1) & 3)) * 8), &Vb[buf][s * 8]);
        }
    };

    stage(0, 0);
    asm volatile("s_waitcnt vmcnt(0)" ::: "memory");
    __builtin_amdgcn_s_barrier();

    const float THR = 10.0f;
    const int kx = (lq & 7) ^ (((lq >> 3) & 3) << 3);
    const int vx = (lq >> 1) & 3;
    int buf = 0;
    for (int t = 0; t < NT; ++t) {
        if (t + 1 < NT) stage(buf ^ 1, t + 1);
        const _Float16* K_ = Kb[buf];
        const _Float16* V_ = Vb[buf];

        // ---- QK: S^T[key=lq][q col], 16 MFMAs ----
        f32x16 sc;
#pragma unroll
        for (int r = 0; r < 16; ++r) sc[r] = 0.f;
#pragma unroll
        for (int ks = 0; ks < 16; ++ks) {
            const int slot = (2 * ks + hi) ^ kx;
            f16x8 Ak = *(const f16x8*)((const char*)K_ + lq * 512 + slot * 16);
            sc = MFMA32(Ak, QB[ks], sc);
        }

        // ---- per-lane online softmax (lane owns q = lq) ----
        float tm[8];
#pragma unroll
        for (int j = 0; j < 8; ++j) tm[j] = fmaxf(sc[j], sc[j + 8]);
#pragma unroll
        for (int s = 4; s > 0; s >>= 1)
#pragma unroll
            for (int j = 0; j < s; ++j) tm[j] = fmaxf(tm[j], tm[j + s]);
        float mx = fmaxf(tm[0], __shfl_xor(tm[0], 32));
        if (__any(mx > m_r + THR)) {
            const float mn = fmaxf(m_r, mx);
            const float scl = fexp2(m_r - mn);
            m_r = mn; l_r *= scl;
#pragma unroll
            for (int i = 0; i < 8; ++i)
#pragma unroll
                for (int r = 0; r < 16; ++r) Oacc[i][r] *= scl;
        }

        float p[16];
#pragma unroll
        for (int r = 0; r < 16; ++r) p[r] = fexp2(sc[r] - m_r);
        float ts[8];
#pragma unroll
        for (int j = 0; j < 8; ++j) ts[j] = p[j] + p[j + 8];
#pragma unroll
        for (int s = 4; s > 0; s >>= 1)
#pragma unroll
            for (int j = 0; j < s; ++j) ts[j] += ts[j + s];
        l_r += ts[0] + __shfl_xor(ts[0], 32);

        unsigned w[8], pw[8];
#pragma unroll
        for (int j = 0; j < 8; ++j) {
            w[j] = packh(p[2 * j], p[2 * j + 1]);
            pw[j] = __shfl_xor(w[j], 32);
        }
        f16x8 Pfrag[2];
#pragma unroll
        for (int s = 0; s < 2; ++s) {
            unsigned f0 = hi ? pw[4 * s + 2] : w[4 * s + 0];
            unsigned f1 = hi ? pw[4 * s + 3] : w[4 * s + 1];
            unsigned f2 = hi ? w[4 * s + 2] : pw[4 * s + 0];
            unsigned f3 = hi ? w[4 * s + 3] : pw[4 * s + 1];
            union { unsigned u[4]; f16x8 f; } cvt;
            cvt.u[0] = f0; cvt.u[1] = f1; cvt.u[2] = f2; cvt.u[3] = f3;
            Pfrag[s] = cvt.f;
        }

        // ---- PV: O^T[d][q] += V^T.P, 16 MFMAs (8 independent chains) ----
#pragma unroll
        for (int dblk = 0; dblk < 8; ++dblk) {
#pragma unroll
            for (int kstep = 0; kstep < 2; ++kstep) {
                const int slot = (kstep * 2 + hi) ^ vx;
                f16x8 Av = *(const f16x8*)((const char*)V_ + (dblk * 32 + lq) * 64 + slot * 16);
                Oacc[dblk] = MFMA32(Av, Pfrag[kstep], Oacc[dblk]);
            }
        }

        asm volatile("s_waitcnt vmcnt(0)" ::: "memory");
        __builtin_amdgcn_s_barrier();
        buf ^= 1;
    }

    // ---- epilogue ----
    _Float16* Ops = (split < 2) ? (Op01 + (size_t)split * 4194304)
                                : (Op23 + (size_t)(split - 2) * 4194304);
    const float inv = 1.0f / l_r;
    const size_t grow = qrow + lq;
#pragma unroll
    for (int dblk = 0; dblk < 8; ++dblk)
#pragma unroll
        for (int quad = 0; quad < 4; ++quad) {
            f16x4 o;
#pragma unroll
            for (int j = 0; j < 4; ++j) o[j] = (_Float16)(Oacc[dblk][quad * 4 + j] * inv);
            *(f16x4*)(Ops + grow * 256 + dblk * 32 + 8 * quad + 4 * hi) = o;
        }
    if (hi == 0) {
        ml[((size_t)split * 16384 + grow) * 2]     = m_r;
        ml[((size_t)split * 16384 + grow) * 2 + 1] = l_r;
    }
}

// ---------------- kernel 4: combine split-K partials (NS=4, 512 blocks) -----
__global__ __launch_bounds__(256) void combine_kernel(
    const _Float16* __restrict__ Op01, const _Float16* __restrict__ Op23,
    const float* __restrict__ ml, float* __restrict__ out)
{
    const int idx = blockIdx.x * 256 + threadIdx.x;   // [0, 131072)
    const int row = idx >> 3, d8 = (idx & 7) * 32;    // 4 chunks of 8 per thread
    float m_s[4], l_s[4], w[4];
    float M = -1e30f;
#pragma unroll
    for (int s = 0; s < 4; ++s) {
        m_s[s] = ml[((size_t)s * 16384 + row) * 2];
        l_s[s] = ml[((size_t)s * 16384 + row) * 2 + 1];
        M = fmaxf(M, m_s[s]);
    }
    float Wsum = 0.f;
#pragma unroll
    for (int s = 0; s < 4; ++s) { w[s] = l_s[s] * fexp2(m_s[s] - M); Wsum += w[s]; }
    const float inv = 1.0f / Wsum;
#pragma unroll
    for (int s = 0; s < 4; ++s) w[s] *= inv;

#pragma unroll
    for (int ch = 0; ch < 4; ++ch) {
        const int d0 = d8 + ch * 8;
        float acc[8] = {0.f, 0.f, 0.f, 0.f, 0.f, 0.f, 0.f, 0.f};
#pragma unroll
        for (int s = 0; s < 4; ++s) {
            const _Float16* Op = (s < 2) ? (Op01 + (size_t)s * 4194304)
                                         : (Op23 + (size_t)(s - 2) * 4194304);
            f16x8 v = *(const f16x8*)(Op + (size_t)row * 256 + d0);
#pragma unroll
            for (int j = 0; j < 8; ++j) acc[j] += w[s] * (float)v[j];
        }
        float4 o0 = {acc[0], acc[1], acc[2], acc[3]};
        float4 o1 = {acc[4], acc[5], acc[6], acc[7]};
        *(float4*)(out + (size_t)row * 256 + d0) = o0;
        *(float4*)(out + (size_t)row * 256 + d0 + 4) = o1;
    }
}

extern "C" void kernel_launch(void* const* d_in, const int* in_sizes, int n_in,
                              void* d_out, int out_size, void* d_ws, size_t ws_size,
                              hipStream_t stream) {
    const float* x  = (const float*)d_in[0];
    const float* Wq = (const float*)d_in[1];
    const float* bq = (const float*)d_in[2];
    const float* Wk = (const float*)d_in[3];
    const float* bk = (const float*)d_in[4];
    const float* Wv = (const float*)d_in[5];
    const float* bv = (const float*)d_in[6];
    float* out = (float*)d_out;

    // ws: Op01 (16MB) | Qf | Kf | Vt | Wth | ml | Op23 (16MB) | cnt
    _Float16* Op01 = (_Float16*)d_ws;
    _Float16* Qf  = Op01 + 2 * 4194304;
    _Float16* Kf  = Qf  + 4194304;
    _Float16* Vt  = Kf  + 4194304;
    _Float16* Wth = Vt  + 4194304;
    float*    ml  = (float*)(Wth + 196608);            // 4*16384*2 f32 = 512KB
    _Float16* Op23 = (_Float16*)((char*)ml + 524288);  // splits 2,3 (16MB)
    int*      cnt  = (int*)(Op23 + 2 * 4194304);       // 8 ints, 256B apart

    convert_w_kernel<<<96, 256, 0, stream>>>(Wq, Wk, Wv, Wth, cnt);
    proj_all_kernel<<<dim3(256, 3), 256, 0, stream>>>(x, Wth, bq, bk, bv, Qf, Kf, Vt);
    attn8_kernel<<<512, 256, 0, stream>>>(Qf, Kf, Vt, Op01, Op23, ml, cnt);
    combine_kernel<<<512, 256, 0, stream>>>(Op01, Op23, ml, out);
}